// Round 1
// baseline (246.185 us; speedup 1.0000x reference)
//
#include <hip/hip_runtime.h>
#include <math.h>

#define N 4096
#define D 256
#define SCALEF 10.0f
#define EPSF 1e-5f
#define MARGIN_INTRA 40.0f
#define MARGIN_INTER 6.0f
#define K_INTRA 4
#define K_INTER 6

// ---------------- Kernel 1: row squared norms ----------------
__global__ __launch_bounds__(64) void sqnorm_kernel(const float* __restrict__ F,
                                                    float* __restrict__ sq) {
    int row = blockIdx.x;
    int lane = threadIdx.x;  // 64 lanes, 4 floats each = 256
    float4 v = ((const float4*)(F + (size_t)row * D))[lane];
    float s = v.x * v.x + v.y * v.y + v.z * v.z + v.w * v.w;
#pragma unroll
    for (int off = 32; off > 0; off >>= 1) s += __shfl_down(s, off, 64);
    if (lane == 0) sq[row] = s;
}

// ---------------- Kernel 2: fp32 tiled GEMM -> dist ----------------
// dist[i][j] = sqrt(max(sq[i]+sq[j]+eps-2*dot(f_i,f_j), 1e-12))
#define BM 64
#define BN 64
#define BK 16

__global__ __launch_bounds__(256) void dist_gemm(const float* __restrict__ F,
                                                 const float* __restrict__ sq,
                                                 float* __restrict__ dist) {
    __shared__ float As[BK][BM];
    __shared__ float Bs[BK][BN];
    int tid = threadIdx.x;
    int i0 = blockIdx.y * BM;
    int j0 = blockIdx.x * BN;
    int tx = tid & 15;   // n dir
    int ty = tid >> 4;   // m dir
    float acc[4][4] = {};
    int lr = tid >> 2;   // row within tile for staging load
    int kq = tid & 3;    // which float4 along k

    for (int kt = 0; kt < D; kt += BK) {
        float4 a = *(const float4*)(F + (size_t)(i0 + lr) * D + kt + kq * 4);
        float4 b = *(const float4*)(F + (size_t)(j0 + lr) * D + kt + kq * 4);
        __syncthreads();  // previous iter's LDS reads must finish
        As[kq * 4 + 0][lr] = a.x; As[kq * 4 + 1][lr] = a.y;
        As[kq * 4 + 2][lr] = a.z; As[kq * 4 + 3][lr] = a.w;
        Bs[kq * 4 + 0][lr] = b.x; Bs[kq * 4 + 1][lr] = b.y;
        Bs[kq * 4 + 2][lr] = b.z; Bs[kq * 4 + 3][lr] = b.w;
        __syncthreads();
#pragma unroll
        for (int kk = 0; kk < BK; ++kk) {
            float av[4], bv[4];
            *(float4*)av = *(const float4*)&As[kk][ty * 4];
            *(float4*)bv = *(const float4*)&Bs[kk][tx * 4];
#pragma unroll
            for (int mi = 0; mi < 4; ++mi)
#pragma unroll
                for (int ni = 0; ni < 4; ++ni) acc[mi][ni] += av[mi] * bv[ni];
        }
    }
#pragma unroll
    for (int mi = 0; mi < 4; ++mi) {
        int i = i0 + ty * 4 + mi;
        float si = sq[i];
#pragma unroll
        for (int ni = 0; ni < 4; ++ni) {
            int j = j0 + tx * 4 + ni;
            float d2 = si + sq[j] + EPSF - 2.0f * acc[mi][ni];
            dist[(size_t)i * N + j] = sqrtf(fmaxf(d2, 1e-12f));
        }
    }
}

// ---------------- Kernel 3: per-row top-(K+1) extraction + LSE + hinge --------
// Each block = one row. 256 threads x 16 strided elements.
// Extract the K+1 largest logits (= K+1 smallest distances) by iterative
// block-argmax; then shifted exp-sum over the remaining elements.
__device__ __forceinline__ float process_partition(float (&l)[16], int K,
                                                   float margin, int tid,
                                                   float* sval, int* saux) {
    unsigned mask = 0xFFFFu;
    float x0 = -INFINITY, shift = -INFINITY;
#pragma unroll 1
    for (int t = 0; t <= K; ++t) {
        float best = -INFINITY;
        int bs = 0;
#pragma unroll
        for (int s = 0; s < 16; ++s) {
            if ((mask >> s) & 1u) {
                if (l[s] > best) { best = l[s]; bs = s; }
            }
        }
        sval[tid] = best;
        saux[tid] = tid * 16 + bs;
        __syncthreads();
        for (int stride = 128; stride > 0; stride >>= 1) {
            if (tid < stride) {
                if (sval[tid + stride] > sval[tid]) {
                    sval[tid] = sval[tid + stride];
                    saux[tid] = saux[tid + stride];
                }
            }
            __syncthreads();
        }
        float win = sval[0];
        int aux = saux[0];
        __syncthreads();  // everyone read winner before next overwrite
        if (t == 0) x0 = win;
        if (t == K) shift = win;
        if ((aux >> 4) == tid) mask &= ~(1u << (aux & 15));
    }
    // LSE over remaining (all <= shift). +1.0 accounts for the shift element.
    float ssum = 0.0f;
#pragma unroll
    for (int s = 0; s < 16; ++s) {
        if ((mask >> s) & 1u) {
            ssum += expf(l[s] - shift);  // -inf -> 0
        }
    }
    sval[tid] = ssum;
    __syncthreads();
    for (int stride = 128; stride > 0; stride >>= 1) {
        if (tid < stride) sval[tid] += sval[tid + stride];
        __syncthreads();
    }
    float h = 0.0f;
    if (tid == 0) {
        if (shift > -INFINITY) {
            float y = shift + logf(1.0f + sval[0]);
            h = fmaxf(-x0 + y + margin, 0.0f);
        }
    }
    __syncthreads();  // sval free for next use
    return h;
}

__global__ __launch_bounds__(256) void rowloss_kernel(const float* __restrict__ dist,
                                                      const int* __restrict__ camid,
                                                      float* __restrict__ rowloss) {
    __shared__ float sval[256];
    __shared__ int saux[256];
    int i = blockIdx.x;
    int tid = threadIdx.x;
    const int ci = camid[i];
    const float* drow = dist + (size_t)i * N;
    float lI[16], lX[16];
#pragma unroll
    for (int s = 0; s < 16; ++s) {
        int j = tid + s * 256;
        float d = drow[j];
        float lg = -SCALEF * d;
        bool intra = (camid[j] == ci);
        lI[s] = intra ? lg : -INFINITY;
        lX[s] = intra ? -INFINITY : lg;
    }
    float h_intra = process_partition(lI, K_INTRA, MARGIN_INTRA, tid, sval, saux);
    float h_inter = process_partition(lX, K_INTER, MARGIN_INTER, tid, sval, saux);
    if (tid == 0) rowloss[i] = h_intra + 0.5f * h_inter;
}

// ---------------- Kernel 4: final reduce ----------------
__global__ __launch_bounds__(256) void final_reduce(const float* __restrict__ rowloss,
                                                    float* __restrict__ out) {
    __shared__ float sbuf[256];
    int tid = threadIdx.x;
    float acc = 0.0f;
#pragma unroll
    for (int s = 0; s < 16; ++s) acc += rowloss[tid + s * 256];
    sbuf[tid] = acc;
    __syncthreads();
    for (int stride = 128; stride > 0; stride >>= 1) {
        if (tid < stride) sbuf[tid] += sbuf[tid + stride];
        __syncthreads();
    }
    if (tid == 0) out[0] = sbuf[0] * (1.0f / (float)N);
}

extern "C" void kernel_launch(void* const* d_in, const int* in_sizes, int n_in,
                              void* d_out, int out_size, void* d_ws, size_t ws_size,
                              hipStream_t stream) {
    const float* F = (const float*)d_in[0];
    const int* camid = (const int*)d_in[1];
    float* out = (float*)d_out;
    char* ws = (char*)d_ws;
    float* dist = (float*)ws;                                  // N*N*4 = 64 MB
    float* sq = (float*)(ws + (size_t)N * N * 4);              // 16 KB
    float* rowloss = (float*)(ws + (size_t)N * N * 4 + N * 4); // 16 KB

    sqnorm_kernel<<<N, 64, 0, stream>>>(F, sq);
    dist_gemm<<<dim3(N / BN, N / BM), 256, 0, stream>>>(F, sq, dist);
    rowloss_kernel<<<N, 256, 0, stream>>>(dist, camid, rowloss);
    final_reduce<<<1, 256, 0, stream>>>(rowloss, out);
}

// Round 2
// 139.241 us; speedup vs baseline: 1.7681x; 1.7681x over previous
//
#include <hip/hip_runtime.h>
#include <hip/hip_bf16.h>
#include <math.h>

#define N 4096
#define D 256
#define SCALEF 10.0f
#define EPSF 1e-5f
#define MARGIN_INTRA 40.0f
#define MARGIN_INTER 6.0f
#define K_INTRA 4
#define K_INTER 6

typedef unsigned short ushort_t;
typedef __attribute__((ext_vector_type(8))) short short8;
typedef __attribute__((ext_vector_type(4))) float floatx4;

__device__ __forceinline__ ushort_t f2bf(float x) {
    __hip_bfloat16 h = __float2bfloat16(x);
    return *reinterpret_cast<ushort_t*>(&h);
}
__device__ __forceinline__ float bf2f(ushort_t u) {
    __hip_bfloat16 h = *reinterpret_cast<__hip_bfloat16*>(&u);
    return __bfloat162float(h);
}

// ---------------- Kernel 1: row squared norms ----------------
__global__ __launch_bounds__(64) void sqnorm_kernel(const float* __restrict__ F,
                                                    float* __restrict__ sq) {
    int row = blockIdx.x;
    int lane = threadIdx.x;
    float4 v = ((const float4*)(F + (size_t)row * D))[lane];
    float s = v.x * v.x + v.y * v.y + v.z * v.z + v.w * v.w;
#pragma unroll
    for (int off = 32; off > 0; off >>= 1) s += __shfl_down(s, off, 64);
    if (lane == 0) sq[row] = s;
}

// ---------------- Kernel 1b: fp32 -> bf16 hi/lo split ----------------
__global__ __launch_bounds__(256) void prep_bf16(const float* __restrict__ F,
                                                 ushort_t* __restrict__ Fhi,
                                                 ushort_t* __restrict__ Flo) {
    int g = blockIdx.x * 256 + threadIdx.x;  // 0 .. N*D/4-1
    float4 v = ((const float4*)F)[g];
    ushort4 h, l;
    h.x = f2bf(v.x); l.x = f2bf(v.x - bf2f(h.x));
    h.y = f2bf(v.y); l.y = f2bf(v.y - bf2f(h.y));
    h.z = f2bf(v.z); l.z = f2bf(v.z - bf2f(h.z));
    h.w = f2bf(v.w); l.w = f2bf(v.w - bf2f(h.w));
    ((ushort4*)Fhi)[g] = h;
    ((ushort4*)Flo)[g] = l;
}

// ---------------- Kernel 2: bf16-split MFMA GEMM -> dist ----------------
// dist[i][j] = sqrt(max(sq[i]+sq[j]+eps-2*dot(f_i,f_j), 1e-12))
// dot via 3-term bf16 split: hi*hi + hi*lo + lo*hi (lo*lo ~ 2^-18, dropped)
// 128x128 tile, BK=32, 4 waves each 64x64 (4x4 frags of 16x16x32 mfma).
#define LDST 40  // padded LDS row stride in bf16 elems (80 B: +4 bank shift/row, 16B-aligned)

__global__ __launch_bounds__(256) void dist_gemm_mfma(const ushort_t* __restrict__ Fhi,
                                                      const ushort_t* __restrict__ Flo,
                                                      const float* __restrict__ sq,
                                                      float* __restrict__ dist) {
    __shared__ ushort_t lds[4][128 * LDST];  // Ahi, Alo, Bhi, Blo = 40960 B
    int tid = threadIdx.x;
    int i0 = blockIdx.y * 128, j0 = blockIdx.x * 128;
    int wave = tid >> 6, lane = tid & 63;
    int wr = wave >> 1, wc = wave & 1;          // wave tile: rows wr*64, cols wc*64
    int lane15 = lane & 15, quad = lane >> 4;

    floatx4 acc[4][4] = {};

    int srow = tid >> 1, shalf = tid & 1;       // staging: 128 rows x 2 halves of 16
    const ushort_t* gAh = Fhi + (size_t)(i0 + srow) * D + shalf * 16;
    const ushort_t* gAl = Flo + (size_t)(i0 + srow) * D + shalf * 16;
    const ushort_t* gBh = Fhi + (size_t)(j0 + srow) * D + shalf * 16;
    const ushort_t* gBl = Flo + (size_t)(j0 + srow) * D + shalf * 16;
    ushort_t* sdst = &lds[0][0] + srow * LDST + shalf * 16;

#pragma unroll 1
    for (int kt = 0; kt < 8; ++kt) {
        int koff = kt * 32;
        short8 ra[2], rb[2], rc[2], rd[2];
#pragma unroll
        for (int q = 0; q < 2; ++q) {
            ra[q] = *(const short8*)(gAh + koff + q * 8);
            rb[q] = *(const short8*)(gAl + koff + q * 8);
            rc[q] = *(const short8*)(gBh + koff + q * 8);
            rd[q] = *(const short8*)(gBl + koff + q * 8);
        }
        __syncthreads();  // previous iteration's LDS reads complete
#pragma unroll
        for (int q = 0; q < 2; ++q) {
            *(short8*)(sdst + 0 * 128 * LDST + q * 8) = ra[q];
            *(short8*)(sdst + 1 * 128 * LDST + q * 8) = rb[q];
            *(short8*)(sdst + 2 * 128 * LDST + q * 8) = rc[q];
            *(short8*)(sdst + 3 * 128 * LDST + q * 8) = rd[q];
        }
        __syncthreads();

        short8 ahi[4], alo[4], bhi[4], blo[4];
        int eoff = quad * 8;
#pragma unroll
        for (int mi = 0; mi < 4; ++mi) {
            int r = wr * 64 + mi * 16 + lane15;
            ahi[mi] = *(const short8*)(&lds[0][0] + r * LDST + eoff);
            alo[mi] = *(const short8*)(&lds[1][0] + r * LDST + eoff);
        }
#pragma unroll
        for (int ni = 0; ni < 4; ++ni) {
            int r = wc * 64 + ni * 16 + lane15;
            bhi[ni] = *(const short8*)(&lds[2][0] + r * LDST + eoff);
            blo[ni] = *(const short8*)(&lds[3][0] + r * LDST + eoff);
        }
#pragma unroll
        for (int mi = 0; mi < 4; ++mi)
#pragma unroll
            for (int ni = 0; ni < 4; ++ni) {
                acc[mi][ni] = __builtin_amdgcn_mfma_f32_16x16x32_bf16(ahi[mi], bhi[ni], acc[mi][ni], 0, 0, 0);
                acc[mi][ni] = __builtin_amdgcn_mfma_f32_16x16x32_bf16(ahi[mi], blo[ni], acc[mi][ni], 0, 0, 0);
                acc[mi][ni] = __builtin_amdgcn_mfma_f32_16x16x32_bf16(alo[mi], bhi[ni], acc[mi][ni], 0, 0, 0);
            }
    }

    // epilogue: C/D layout col=lane&15, row=quad*4+reg
#pragma unroll
    for (int mi = 0; mi < 4; ++mi) {
        int ibase = i0 + wr * 64 + mi * 16 + quad * 4;
        float si[4];
#pragma unroll
        for (int r = 0; r < 4; ++r) si[r] = sq[ibase + r];
#pragma unroll
        for (int ni = 0; ni < 4; ++ni) {
            int j = j0 + wc * 64 + ni * 16 + lane15;
            float sj = sq[j];
#pragma unroll
            for (int r = 0; r < 4; ++r) {
                float d2 = si[r] + sj + EPSF - 2.0f * acc[mi][ni][r];
                dist[(size_t)(ibase + r) * N + j] = sqrtf(fmaxf(d2, 1e-12f));
            }
        }
    }
}

// ---------------- Kernel 2-alt: fp32 fallback GEMM (if ws too small) ----------------
#define BM 64
#define BN 64
#define BK 16
__global__ __launch_bounds__(256) void dist_gemm(const float* __restrict__ F,
                                                 const float* __restrict__ sq,
                                                 float* __restrict__ dist) {
    __shared__ float As[BK][BM];
    __shared__ float Bs[BK][BN];
    int tid = threadIdx.x;
    int i0 = blockIdx.y * BM;
    int j0 = blockIdx.x * BN;
    int tx = tid & 15, ty = tid >> 4;
    float acc[4][4] = {};
    int lr = tid >> 2, kq = tid & 3;
    for (int kt = 0; kt < D; kt += BK) {
        float4 a = *(const float4*)(F + (size_t)(i0 + lr) * D + kt + kq * 4);
        float4 b = *(const float4*)(F + (size_t)(j0 + lr) * D + kt + kq * 4);
        __syncthreads();
        As[kq * 4 + 0][lr] = a.x; As[kq * 4 + 1][lr] = a.y;
        As[kq * 4 + 2][lr] = a.z; As[kq * 4 + 3][lr] = a.w;
        Bs[kq * 4 + 0][lr] = b.x; Bs[kq * 4 + 1][lr] = b.y;
        Bs[kq * 4 + 2][lr] = b.z; Bs[kq * 4 + 3][lr] = b.w;
        __syncthreads();
#pragma unroll
        for (int kk = 0; kk < BK; ++kk) {
            float av[4], bv[4];
            *(float4*)av = *(const float4*)&As[kk][ty * 4];
            *(float4*)bv = *(const float4*)&Bs[kk][tx * 4];
#pragma unroll
            for (int mi = 0; mi < 4; ++mi)
#pragma unroll
                for (int ni = 0; ni < 4; ++ni) acc[mi][ni] += av[mi] * bv[ni];
        }
    }
#pragma unroll
    for (int mi = 0; mi < 4; ++mi) {
        int i = i0 + ty * 4 + mi;
        float s_i = sq[i];
#pragma unroll
        for (int ni = 0; ni < 4; ++ni) {
            int j = j0 + tx * 4 + ni;
            float d2 = s_i + sq[j] + EPSF - 2.0f * acc[mi][ni];
            dist[(size_t)i * N + j] = sqrtf(fmaxf(d2, 1e-12f));
        }
    }
}

// ---------------- Kernel 3: wave-per-row top-(K+1) + threshold LSE + hinge ----------
template <int L>
__device__ __forceinline__ void bubble_insert(float (&t)[L], float v) {
#pragma unroll
    for (int q = 0; q < L; ++q) {
        float hi = fmaxf(t[q], v);
        v = fminf(t[q], v);
        t[q] = hi;
    }
}

// merge two sorted-desc L-lists, keep top-L in a. k-th largest of union =
// max over i+j=k+1 of min(a[i-1] | +inf, b[j-1] | +inf).
template <int L>
__device__ __forceinline__ void merge_sorted(float (&a)[L], const float (&b)[L]) {
    float c[L];
#pragma unroll
    for (int k = 0; k < L; ++k) {
        float m = fmaxf(a[k], b[k]);
#pragma unroll
        for (int i = 1; i <= k; ++i) m = fmaxf(m, fminf(a[i - 1], b[k - i]));
        c[k] = m;
    }
#pragma unroll
    for (int k = 0; k < L; ++k) a[k] = c[k];
}

__global__ __launch_bounds__(256) void rowloss2(const float* __restrict__ dist,
                                                const int* __restrict__ camid,
                                                float* __restrict__ rowloss) {
    int wave = threadIdx.x >> 6, lane = threadIdx.x & 63;
    int row = blockIdx.x * 4 + wave;
    const float4* dr4 = (const float4*)(dist + (size_t)row * N);
    const int4* cam4 = (const int4*)camid;
    const int ci = camid[row];

    float tI[K_INTRA + 1], tX[K_INTER + 1];
#pragma unroll
    for (int q = 0; q <= K_INTRA; ++q) tI[q] = -INFINITY;
#pragma unroll
    for (int q = 0; q <= K_INTER; ++q) tX[q] = -INFINITY;

    // phase 1: per-thread top-L of 64 strided elements
#pragma unroll 1
    for (int s = 0; s < 16; ++s) {
        float4 d4 = dr4[s * 64 + lane];
        int4 c4 = cam4[s * 64 + lane];
        float lg;
        bool ii;
        lg = -SCALEF * d4.x; ii = (c4.x == ci);
        bubble_insert(tI, ii ? lg : -INFINITY); bubble_insert(tX, ii ? -INFINITY : lg);
        lg = -SCALEF * d4.y; ii = (c4.y == ci);
        bubble_insert(tI, ii ? lg : -INFINITY); bubble_insert(tX, ii ? -INFINITY : lg);
        lg = -SCALEF * d4.z; ii = (c4.z == ci);
        bubble_insert(tI, ii ? lg : -INFINITY); bubble_insert(tX, ii ? -INFINITY : lg);
        lg = -SCALEF * d4.w; ii = (c4.w == ci);
        bubble_insert(tI, ii ? lg : -INFINITY); bubble_insert(tX, ii ? -INFINITY : lg);
    }

    // wave butterfly merge -> all lanes hold global top-L
#pragma unroll
    for (int off = 32; off >= 1; off >>= 1) {
        float oI[K_INTRA + 1], oX[K_INTER + 1];
#pragma unroll
        for (int q = 0; q <= K_INTRA; ++q) oI[q] = __shfl_xor(tI[q], off, 64);
        merge_sorted(tI, oI);
#pragma unroll
        for (int q = 0; q <= K_INTER; ++q) oX[q] = __shfl_xor(tX[q], off, 64);
        merge_sorted(tX, oX);
    }
    float x0I = tI[0], shI = tI[K_INTRA];
    float x0X = tX[0], shX = tX[K_INTER];

    // phase 2: threshold-based exclusion with exact tie counts
    float sI = 0.0f, sX = 0.0f;
    int eqI = 0, gtI = 0, eqX = 0, gtX = 0;
#pragma unroll 1
    for (int s = 0; s < 16; ++s) {
        float4 d4 = dr4[s * 64 + lane];
        int4 c4 = cam4[s * 64 + lane];
        float lgs[4] = {-SCALEF * d4.x, -SCALEF * d4.y, -SCALEF * d4.z, -SCALEF * d4.w};
        int cms[4] = {c4.x, c4.y, c4.z, c4.w};
#pragma unroll
        for (int c = 0; c < 4; ++c) {
            bool ii = (cms[c] == ci);
            float vI = ii ? lgs[c] : -INFINITY;
            float vX = ii ? -INFINITY : lgs[c];
            if (vI < shI) sI += __expf(vI - shI);
            eqI += (vI == shI); gtI += (vI > shI);
            if (vX < shX) sX += __expf(vX - shX);
            eqX += (vX == shX); gtX += (vX > shX);
        }
    }
#pragma unroll
    for (int off = 32; off >= 1; off >>= 1) {
        sI += __shfl_xor(sI, off, 64);
        sX += __shfl_xor(sX, off, 64);
        eqI += __shfl_xor(eqI, off, 64);
        gtI += __shfl_xor(gtI, off, 64);
        eqX += __shfl_xor(eqX, off, 64);
        gtX += __shfl_xor(gtX, off, 64);
    }
    if (lane == 0) {
        float h1 = 0.0f, h2 = 0.0f;
        if (shI > -INFINITY) {
            float rest = sI + (float)(eqI - (K_INTRA - gtI));  // included shift-copies
            h1 = fmaxf(shI + logf(rest) - x0I + MARGIN_INTRA, 0.0f);
        }
        if (shX > -INFINITY) {
            float rest = sX + (float)(eqX - (K_INTER - gtX));
            h2 = fmaxf(shX + logf(rest) - x0X + MARGIN_INTER, 0.0f);
        }
        rowloss[row] = h1 + 0.5f * h2;
    }
}

// ---------------- Kernel 4: final reduce ----------------
__global__ __launch_bounds__(256) void final_reduce(const float* __restrict__ rowloss,
                                                    float* __restrict__ out) {
    __shared__ float sbuf[256];
    int tid = threadIdx.x;
    float acc = 0.0f;
#pragma unroll
    for (int s = 0; s < 16; ++s) acc += rowloss[tid + s * 256];
    sbuf[tid] = acc;
    __syncthreads();
    for (int stride = 128; stride > 0; stride >>= 1) {
        if (tid < stride) sbuf[tid] += sbuf[tid + stride];
        __syncthreads();
    }
    if (tid == 0) out[0] = sbuf[0] * (1.0f / (float)N);
}

extern "C" void kernel_launch(void* const* d_in, const int* in_sizes, int n_in,
                              void* d_out, int out_size, void* d_ws, size_t ws_size,
                              hipStream_t stream) {
    const float* F = (const float*)d_in[0];
    const int* camid = (const int*)d_in[1];
    float* out = (float*)d_out;
    char* ws = (char*)d_ws;
    const size_t DIST_BYTES = (size_t)N * N * 4;
    float* dist = (float*)ws;
    float* sq = (float*)(ws + DIST_BYTES);
    float* rowloss = (float*)(ws + DIST_BYTES + 16384);
    ushort_t* Fhi = (ushort_t*)(ws + DIST_BYTES + 32768);
    ushort_t* Flo = Fhi + (size_t)N * D;
    const size_t needed = DIST_BYTES + 32768 + 2 * (size_t)N * D * sizeof(ushort_t);

    sqnorm_kernel<<<N, 64, 0, stream>>>(F, sq);
    if (ws_size >= needed) {
        prep_bf16<<<(N * D / 4) / 256, 256, 0, stream>>>(F, Fhi, Flo);
        dist_gemm_mfma<<<dim3(N / 128, N / 128), 256, 0, stream>>>(Fhi, Flo, sq, dist);
    } else {
        dist_gemm<<<dim3(N / BN, N / BM), 256, 0, stream>>>(F, sq, dist);
    }
    rowloss2<<<N / 4, 256, 0, stream>>>(dist, camid, rowloss);
    final_reduce<<<1, 256, 0, stream>>>(rowloss, out);
}

// Round 4
// 130.292 us; speedup vs baseline: 1.8895x; 1.0687x over previous
//
#include <hip/hip_runtime.h>
#include <hip/hip_bf16.h>
#include <math.h>

#define N 4096
#define D 256
#define SCALEF 10.0f
#define EPSF 1e-5f
#define MARGIN_INTRA 40.0f
#define MARGIN_INTER 6.0f
// reference excludes sorted_intra[0:4] = diagonal + top-3 non-diag, sorted_inter[0:6]
#define LI 3
#define LX 6
#define NCHUNK 16   // j-chunks of 256
#define NSTRIP 32   // i-strips of 128
#define PPARTS (NCHUNK * 2)  // partial per (chunk, wr)

typedef unsigned short ushort_t;
typedef __attribute__((ext_vector_type(8))) short short8;
typedef __attribute__((ext_vector_type(4))) float floatx4;

__device__ __forceinline__ ushort_t f2bf(float x) {
    __hip_bfloat16 h = __float2bfloat16(x);
    return *reinterpret_cast<ushort_t*>(&h);
}
__device__ __forceinline__ float bf2f(ushort_t u) {
    __hip_bfloat16 h = *reinterpret_cast<__hip_bfloat16*>(&u);
    return __bfloat162float(h);
}

template <int L>
__device__ __forceinline__ void bubble_insert(float (&t)[L], float v) {
#pragma unroll
    for (int q = 0; q < L; ++q) {
        float hi = fmaxf(t[q], v);
        v = fminf(t[q], v);
        t[q] = hi;
    }
}

// ---------------- Kernel 1: per-row sq, R, bf16 hi/lo split ----------------
__global__ __launch_bounds__(64) void prep_kernel(const float* __restrict__ F,
                                                  ushort_t* __restrict__ Fhi,
                                                  ushort_t* __restrict__ Flo,
                                                  float* __restrict__ sq,
                                                  float* __restrict__ Rrow) {
    int row = blockIdx.x;
    int lane = threadIdx.x;
    float4 v = ((const float4*)(F + (size_t)row * D))[lane];
    ushort4 h, l;
    h.x = f2bf(v.x); l.x = f2bf(v.x - bf2f(h.x));
    h.y = f2bf(v.y); l.y = f2bf(v.y - bf2f(h.y));
    h.z = f2bf(v.z); l.z = f2bf(v.z - bf2f(h.z));
    h.w = f2bf(v.w); l.w = f2bf(v.w - bf2f(h.w));
    ((ushort4*)(Fhi + (size_t)row * D))[lane] = h;
    ((ushort4*)(Flo + (size_t)row * D))[lane] = l;
    float s = v.x * v.x + v.y * v.y + v.z * v.z + v.w * v.w;
#pragma unroll
    for (int off = 32; off > 0; off >>= 1) s += __shfl_down(s, off, 64);
    if (lane == 0) {
        sq[row] = s;
        Rrow[row] = -SCALEF * sqrtf(2.0f * s);  // per-row exp reference shift
    }
}

// ---------------- Kernel 2: fused GEMM + online masked-topk-LSE ----------------
// Block: 128 rows (i) x 256 cols (j). Gram tile computed TRANSPOSED:
// MFMA A-operand <- j-features, B-operand <- i-features, so each lane's
// accumulator holds 4 rows (ni) x 16 cols. Per-lane state streams over j.
#define LDST 40  // padded LDS row stride (80 B -> only 2-way bank aliasing, free)

__global__ __launch_bounds__(256, 2) void fused_kernel(
    const ushort_t* __restrict__ Fhi, const ushort_t* __restrict__ Flo,
    const float* __restrict__ sq, const float* __restrict__ Rrow,
    const int* __restrict__ camid,
    float4* __restrict__ partA, float4* __restrict__ partB, float4* __restrict__ partC) {
    __shared__ ushort_t lds[4][128 * LDST];  // Ajhi, Ajlo, Bihi, Bilo = 40960 B
    int tid = threadIdx.x;
    int wave = tid >> 6, lane = tid & 63;
    int wr = wave >> 1, wc = wave & 1;   // wr: j-half of tile, wc: i-half
    int lane15 = lane & 15, quad = lane >> 4;
    int cid = blockIdx.x, sid = blockIdx.y;
    int i0 = sid * 128, j00 = cid * 256;

    // per-lane row info (4 rows: ni = 0..3)
    float si[4], Ri4[4];
    int ci4[4], ig[4];
#pragma unroll
    for (int ni = 0; ni < 4; ++ni) {
        int i = i0 + wc * 64 + ni * 16 + lane15;
        ig[ni] = i;
        si[ni] = sq[i];
        Ri4[ni] = Rrow[i];
        ci4[ni] = camid[i];
    }

    float tI[4][LI], tX[4][LX], sIa[4], sXa[4];
#pragma unroll
    for (int ni = 0; ni < 4; ++ni) {
#pragma unroll
        for (int q = 0; q < LI; ++q) tI[ni][q] = -INFINITY;
#pragma unroll
        for (int q = 0; q < LX; ++q) tX[ni][q] = -INFINITY;
        sIa[ni] = 0.0f; sXa[ni] = 0.0f;
    }

    int srow = tid >> 1, shalf = tid & 1;
    const ushort_t* gBh = Fhi + (size_t)(i0 + srow) * D + shalf * 16;
    const ushort_t* gBl = Flo + (size_t)(i0 + srow) * D + shalf * 16;
    ushort_t* sdst = &lds[0][0] + srow * LDST + shalf * 16;

#pragma unroll 1
    for (int jt = 0; jt < 2; ++jt) {
        int j0 = j00 + jt * 128;
        const ushort_t* gAh = Fhi + (size_t)(j0 + srow) * D + shalf * 16;
        const ushort_t* gAl = Flo + (size_t)(j0 + srow) * D + shalf * 16;
        floatx4 acc[4][4] = {};

#pragma unroll 1
        for (int kt = 0; kt < 8; ++kt) {
            int koff = kt * 32;
            short8 ra[2], rb[2], rc[2], rd[2];
#pragma unroll
            for (int q = 0; q < 2; ++q) {
                ra[q] = *(const short8*)(gAh + koff + q * 8);
                rb[q] = *(const short8*)(gAl + koff + q * 8);
                rc[q] = *(const short8*)(gBh + koff + q * 8);
                rd[q] = *(const short8*)(gBl + koff + q * 8);
            }
            __syncthreads();
#pragma unroll
            for (int q = 0; q < 2; ++q) {
                *(short8*)(sdst + 0 * 128 * LDST + q * 8) = ra[q];
                *(short8*)(sdst + 1 * 128 * LDST + q * 8) = rb[q];
                *(short8*)(sdst + 2 * 128 * LDST + q * 8) = rc[q];
                *(short8*)(sdst + 3 * 128 * LDST + q * 8) = rd[q];
            }
            __syncthreads();

            short8 ahi[4], alo[4], bhi[4], blo[4];
            int eoff = quad * 8;
#pragma unroll
            for (int mi = 0; mi < 4; ++mi) {
                int r = wr * 64 + mi * 16 + lane15;  // j-side rows
                ahi[mi] = *(const short8*)(&lds[0][0] + r * LDST + eoff);
                alo[mi] = *(const short8*)(&lds[1][0] + r * LDST + eoff);
            }
#pragma unroll
            for (int ni = 0; ni < 4; ++ni) {
                int r = wc * 64 + ni * 16 + lane15;  // i-side rows
                bhi[ni] = *(const short8*)(&lds[2][0] + r * LDST + eoff);
                blo[ni] = *(const short8*)(&lds[3][0] + r * LDST + eoff);
            }
#pragma unroll
            for (int mi = 0; mi < 4; ++mi)
#pragma unroll
                for (int ni = 0; ni < 4; ++ni) {
                    acc[mi][ni] = __builtin_amdgcn_mfma_f32_16x16x32_bf16(ahi[mi], bhi[ni], acc[mi][ni], 0, 0, 0);
                    acc[mi][ni] = __builtin_amdgcn_mfma_f32_16x16x32_bf16(ahi[mi], blo[ni], acc[mi][ni], 0, 0, 0);
                    acc[mi][ni] = __builtin_amdgcn_mfma_f32_16x16x32_bf16(alo[mi], bhi[ni], acc[mi][ni], 0, 0, 0);
                }
        }

        // epilogue: acc[mi][ni][r] <-> (j = j0 + wr*64 + mi*16 + quad*4 + r,
        //                               i = ig[ni])
#pragma unroll
        for (int mi = 0; mi < 4; ++mi) {
            int jg0 = j0 + wr * 64 + mi * 16 + quad * 4;
            float4 sj4 = *(const float4*)(sq + jg0);
            int4 cj4 = *(const int4*)(camid + jg0);
            const float* sjp = (const float*)&sj4;
            const int* cjp = (const int*)&cj4;
#pragma unroll
            for (int ni = 0; ni < 4; ++ni) {
                int dd = jg0 - ig[ni];  // diagonal at r == -dd
#pragma unroll
                for (int r = 0; r < 4; ++r) {
                    float d2 = si[ni] + sjp[r] + EPSF - 2.0f * acc[mi][ni][r];
                    float d = sqrtf(fmaxf(d2, 1e-12f));
                    float x = -SCALEF * d;
                    float e = __expf(x - Ri4[ni]);
                    bool ii = (cjp[r] == ci4[ni]);
                    bool dg = ((dd + r) == 0);
                    bool okI = ii && !dg;
                    sIa[ni] += okI ? e : 0.0f;
                    sXa[ni] += ii ? 0.0f : e;
                    bubble_insert<LI>(tI[ni], okI ? x : -INFINITY);
                    bubble_insert<LX>(tX[ni], ii ? -INFINITY : x);
                }
            }
        }
    }

    // merge across the 4 quads sharing each row (butterfly, offsets 16 & 32).
    // CRITICAL: snapshot ALL partner values BEFORE mutating own lists — lanes
    // run in lockstep, so interleaving shfl with insert reads corrupted state.
#pragma unroll
    for (int off = 16; off <= 32; off <<= 1) {
#pragma unroll
        for (int ni = 0; ni < 4; ++ni) {
            sIa[ni] += __shfl_xor(sIa[ni], off, 64);
            sXa[ni] += __shfl_xor(sXa[ni], off, 64);
            float oI[LI], oX[LX];
#pragma unroll
            for (int q = 0; q < LI; ++q) oI[q] = __shfl_xor(tI[ni][q], off, 64);
#pragma unroll
            for (int q = 0; q < LX; ++q) oX[q] = __shfl_xor(tX[ni][q], off, 64);
#pragma unroll
            for (int q = 0; q < LI; ++q) bubble_insert<LI>(tI[ni], oI[q]);
#pragma unroll
            for (int q = 0; q < LX; ++q) bubble_insert<LX>(tX[ni], oX[q]);
        }
    }

    if (quad == 0) {
        int p = cid * 2 + wr;
#pragma unroll
        for (int ni = 0; ni < 4; ++ni) {
            size_t idx = (size_t)p * N + ig[ni];
            partA[idx] = make_float4(tI[ni][0], tI[ni][1], tI[ni][2], sIa[ni]);
            partB[idx] = make_float4(tX[ni][0], tX[ni][1], tX[ni][2], tX[ni][3]);
            partC[idx] = make_float4(tX[ni][4], tX[ni][5], sXa[ni], 0.0f);
        }
    }
}

// ---------------- Kernel 3: merge partials -> per-row loss ----------------
__global__ __launch_bounds__(256) void merge_kernel(const float4* __restrict__ partA,
                                                    const float4* __restrict__ partB,
                                                    const float4* __restrict__ partC,
                                                    const float* __restrict__ Rrow,
                                                    float* __restrict__ rowloss) {
    int row = blockIdx.x * 256 + threadIdx.x;
    float mI[LI] = {-INFINITY, -INFINITY, -INFINITY};
    float mX[LX] = {-INFINITY, -INFINITY, -INFINITY, -INFINITY, -INFINITY, -INFINITY};
    float SI = 0.0f, SX = 0.0f;
#pragma unroll 1
    for (int p = 0; p < PPARTS; ++p) {
        size_t idx = (size_t)p * N + row;
        float4 a = partA[idx];
        float4 b = partB[idx];
        float4 c = partC[idx];
        bubble_insert<LI>(mI, a.x); bubble_insert<LI>(mI, a.y); bubble_insert<LI>(mI, a.z);
        SI += a.w;
        bubble_insert<LX>(mX, b.x); bubble_insert<LX>(mX, b.y);
        bubble_insert<LX>(mX, b.z); bubble_insert<LX>(mX, b.w);
        bubble_insert<LX>(mX, c.x); bubble_insert<LX>(mX, c.y);
        SX += c.z;
    }
    float R = Rrow[row];
    // intra: exclude diag (by construction) + top-3 values
    float subI = __expf(mI[0] - R) + __expf(mI[1] - R) + __expf(mI[2] - R);
    float restI = fmaxf(SI - subI, 1e-37f);
    float yI = R + logf(restI);
    float hI = fmaxf(yI + SCALEF * sqrtf(EPSF) + MARGIN_INTRA, 0.0f);  // -x0 = +10*sqrt(eps)
    // inter: exclude top-6 values
    float subX = __expf(mX[0] - R) + __expf(mX[1] - R) + __expf(mX[2] - R) +
                 __expf(mX[3] - R) + __expf(mX[4] - R) + __expf(mX[5] - R);
    float restX = fmaxf(SX - subX, 1e-37f);
    float yX = R + logf(restX);
    float hX = fmaxf(-mX[0] + yX + MARGIN_INTER, 0.0f);
    rowloss[row] = hI + 0.5f * hX;
}

// ---------------- Kernel 4: final reduce ----------------
__global__ __launch_bounds__(256) void final_reduce(const float* __restrict__ rowloss,
                                                    float* __restrict__ out) {
    __shared__ float sbuf[256];
    int tid = threadIdx.x;
    float acc = 0.0f;
#pragma unroll
    for (int s = 0; s < 16; ++s) acc += rowloss[tid + s * 256];
    sbuf[tid] = acc;
    __syncthreads();
    for (int stride = 128; stride > 0; stride >>= 1) {
        if (tid < stride) sbuf[tid] += sbuf[tid + stride];
        __syncthreads();
    }
    if (tid == 0) out[0] = sbuf[0] * (1.0f / (float)N);
}

extern "C" void kernel_launch(void* const* d_in, const int* in_sizes, int n_in,
                              void* d_out, int out_size, void* d_ws, size_t ws_size,
                              hipStream_t stream) {
    const float* F = (const float*)d_in[0];
    const int* camid = (const int*)d_in[1];
    float* out = (float*)d_out;
    char* ws = (char*)d_ws;

    ushort_t* Fhi = (ushort_t*)ws;                               // 2 MB
    ushort_t* Flo = Fhi + (size_t)N * D;                         // 2 MB
    float* sq = (float*)(ws + 2 * (size_t)N * D * 2);            // 16 KB
    float* Rrow = sq + N;                                        // 16 KB
    float* rowloss = Rrow + N;                                   // 16 KB
    float4* partA = (float4*)(ws + 2 * (size_t)N * D * 2 + 3 * N * 4);  // 2 MB each
    float4* partB = partA + (size_t)PPARTS * N;
    float4* partC = partB + (size_t)PPARTS * N;

    prep_kernel<<<N, 64, 0, stream>>>(F, Fhi, Flo, sq, Rrow);
    fused_kernel<<<dim3(NCHUNK, NSTRIP), 256, 0, stream>>>(Fhi, Flo, sq, Rrow, camid,
                                                           partA, partB, partC);
    merge_kernel<<<N / 256, 256, 0, stream>>>(partA, partB, partC, Rrow, rowloss);
    final_reduce<<<1, 256, 0, stream>>>(rowloss, out);
}